// Round 1
// baseline (1817.613 us; speedup 1.0000x reference)
//
#include <hip/hip_runtime.h>
#include <stdint.h>

#define E_  8
#define D_  1024
#define H_  4096
#define T_  32768
#define TPE 4096   // tokens per expert (uniform splits)

typedef __bf16 bf16x8 __attribute__((ext_vector_type(8)));
typedef float  f32x4  __attribute__((ext_vector_type(4)));
typedef unsigned short u16x4 __attribute__((ext_vector_type(4)));
typedef unsigned short u16x8 __attribute__((ext_vector_type(8)));

__device__ __forceinline__ unsigned short f2bf(float f) {
  union { float f; uint32_t u; } v; v.f = f;
  uint32_t u = v.u;
  return (unsigned short)((u + 0x7FFFu + ((u >> 16) & 1u)) >> 16);  // RNE
}

// async global->LDS, 16B per lane; LDS dest = wave-uniform base + lane*16
__device__ __forceinline__ void gld16(const unsigned short* g, unsigned short* l) {
  __builtin_amdgcn_global_load_lds(
      (const __attribute__((address_space(1))) unsigned int*)g,
      (__attribute__((address_space(3))) unsigned int*)l, 16, 0, 0);
}

__device__ __forceinline__ f32x4 mfma_bf16(bf16x8 a, bf16x8 b, f32x4 c) {
  return __builtin_amdgcn_mfma_f32_16x16x32_bf16(a, b, c, 0, 0, 0);
}

// ---------------- fp32 -> bf16 straight convert (x) ----------------
__global__ void cvt_bf16(const float* __restrict__ in, unsigned short* __restrict__ out) {
  size_t i = ((size_t)blockIdx.x * 256 + threadIdx.x) * 8;
  float4 a = *(const float4*)(in + i);
  float4 b = *(const float4*)(in + i + 4);
  u16x8 o;
  o[0] = f2bf(a.x); o[1] = f2bf(a.y); o[2] = f2bf(a.z); o[3] = f2bf(a.w);
  o[4] = f2bf(b.x); o[5] = f2bf(b.y); o[6] = f2bf(b.z); o[7] = f2bf(b.w);
  *(u16x8*)(out + i) = o;
}

// ------------- fp32 [R][C] -> bf16 [C][R] per expert (blockIdx.z) -------------
__global__ void transpose_bf16(const float* __restrict__ in, unsigned short* __restrict__ out,
                               int R, int C) {
  __shared__ unsigned short t[64][68];   // [c_local][r_local], padded stride 68 (8B-aligned rows)
  size_t eo = (size_t)blockIdx.z * R * C;
  const float* ine = in + eo;
  unsigned short* oute = out + eo;
  int r0 = blockIdx.y * 64, c0 = blockIdx.x * 64;
  int rl = threadIdx.x >> 4;        // 0..15
  int cl = (threadIdx.x & 15) * 4;  // 0..60
#pragma unroll
  for (int i = 0; i < 4; ++i) {
    int r = i * 16 + rl;
    float4 v = *(const float4*)(ine + (size_t)(r0 + r) * C + c0 + cl);
    t[cl + 0][r] = f2bf(v.x);
    t[cl + 1][r] = f2bf(v.y);
    t[cl + 2][r] = f2bf(v.z);
    t[cl + 3][r] = f2bf(v.w);
  }
  __syncthreads();
#pragma unroll
  for (int i = 0; i < 4; ++i) {
    int c = i * 16 + rl;
    *(u16x4*)(oute + (size_t)(c0 + c) * R + r0 + cl) = *(const u16x4*)&t[c][cl];
  }
}

// ---------------- GEMM1: gate/up fused + SwiGLU -> h (bf16) ----------------
// A = xb [TPE][D_] row-major (k-contig); B1/B2 = w1t/w3t [H_][D_] (B^T, k-contig)
// LDS tiles stored in MFMA-fragment order: chunk g (1KB) = 16 rows x 32 k,
// position (lane=c*16+r)*16B holds row r, k-chunk c (8 bf16).
__global__ __launch_bounds__(256, 2) void gemm_gateup(
    const unsigned short* __restrict__ xb,
    const unsigned short* __restrict__ w1t,
    const unsigned short* __restrict__ w3t,
    unsigned short* __restrict__ hbuf) {
  __shared__ __align__(16) unsigned short sm[12288];  // sA | sB1 | sB2 (4096 ushorts each)
  unsigned short* sA  = sm;
  unsigned short* sB1 = sm + 4096;
  unsigned short* sB2 = sm + 8192;

  const int e  = blockIdx.z;
  const int m0 = blockIdx.x * 128;
  const int n0 = blockIdx.y * 128;
  const unsigned short* Ae  = xb  + (size_t)e * TPE * D_;
  const unsigned short* B1e = w1t + (size_t)e * D_ * H_;
  const unsigned short* B2e = w3t + (size_t)e * D_ * H_;

  const int tid  = threadIdx.x;
  const int w    = tid >> 6;
  const int lane = tid & 63;
  const int wr = w >> 1, wc = w & 1;
  const int lr = lane & 15;   // row/col within 16
  const int lk = lane >> 4;   // k-chunk quad

  const int g0 = 2 * w, g1 = 2 * w + 1;  // chunks this wave stages
  const unsigned short* ga0  = Ae  + (size_t)(m0 + g0 * 16 + lr) * D_ + lk * 8;
  const unsigned short* ga1  = Ae  + (size_t)(m0 + g1 * 16 + lr) * D_ + lk * 8;
  const unsigned short* gb10 = B1e + (size_t)(n0 + g0 * 16 + lr) * D_ + lk * 8;
  const unsigned short* gb11 = B1e + (size_t)(n0 + g1 * 16 + lr) * D_ + lk * 8;
  const unsigned short* gb20 = B2e + (size_t)(n0 + g0 * 16 + lr) * D_ + lk * 8;
  const unsigned short* gb21 = B2e + (size_t)(n0 + g1 * 16 + lr) * D_ + lk * 8;
  unsigned short* la0  = sA  + g0 * 512;
  unsigned short* la1  = sA  + g1 * 512;
  unsigned short* lb10 = sB1 + g0 * 512;
  unsigned short* lb11 = sB1 + g1 * 512;
  unsigned short* lb20 = sB2 + g0 * 512;
  unsigned short* lb21 = sB2 + g1 * 512;

  const unsigned short* rA  = sA  + (wr * 4) * 512 + lane * 8;
  const unsigned short* rB1 = sB1 + (wc * 4) * 512 + lane * 8;
  const unsigned short* rB2 = sB2 + (wc * 4) * 512 + lane * 8;

  f32x4 accG[4][4] = {}, accU[4][4] = {};

  for (int kt = 0; kt < D_ / 32; ++kt) {
    const int ko = kt * 32;
    gld16(ga0 + ko, la0);
    gld16(ga1 + ko, la1);
    gld16(gb10 + ko, lb10);
    gld16(gb11 + ko, lb11);
    gld16(gb20 + ko, lb20);
    gld16(gb21 + ko, lb21);
    __syncthreads();
    bf16x8 af[4], b1f[4], b2f[4];
#pragma unroll
    for (int i = 0; i < 4; ++i) af[i]  = *(const bf16x8*)(rA + i * 512);
#pragma unroll
    for (int j = 0; j < 4; ++j) b1f[j] = *(const bf16x8*)(rB1 + j * 512);
#pragma unroll
    for (int j = 0; j < 4; ++j) b2f[j] = *(const bf16x8*)(rB2 + j * 512);
#pragma unroll
    for (int i = 0; i < 4; ++i)
#pragma unroll
      for (int j = 0; j < 4; ++j) {
        accG[i][j] = mfma_bf16(af[i], b1f[j], accG[i][j]);
        accU[i][j] = mfma_bf16(af[i], b2f[j], accU[i][j]);
      }
    __syncthreads();
  }

  // epilogue: h = silu(gate) * up, bf16. C/D layout: col=lane&15, row=(lane>>4)*4+reg
  unsigned short* He = hbuf + (size_t)e * TPE * H_;
  const int rbase = m0 + wr * 64;
  const int cbase = n0 + wc * 64;
#pragma unroll
  for (int i = 0; i < 4; ++i)
#pragma unroll
    for (int j = 0; j < 4; ++j)
#pragma unroll
      for (int r = 0; r < 4; ++r) {
        float g = accG[i][j][r];
        float u = accU[i][j][r];
        float hv = (g / (1.0f + __expf(-g))) * u;
        int row = rbase + i * 16 + lk * 4 + r;
        int col = cbase + j * 16 + lr;
        He[(size_t)row * H_ + col] = f2bf(hv);
      }
}

// ---------------- GEMM2: out = h @ w2 (fp32 out) ----------------
// A = h [TPE][H_] (k-contig); B = w2t [D_][H_] (B^T, k-contig)
__global__ __launch_bounds__(256, 2) void gemm_down(
    const unsigned short* __restrict__ hbuf,
    const unsigned short* __restrict__ w2t,
    float* __restrict__ out) {
  __shared__ __align__(16) unsigned short sm[8192];  // sA | sB
  unsigned short* sA = sm;
  unsigned short* sB = sm + 4096;

  const int e  = blockIdx.z;
  const int m0 = blockIdx.x * 128;
  const int n0 = blockIdx.y * 128;
  const unsigned short* Ae = hbuf + (size_t)e * TPE * H_;
  const unsigned short* Be = w2t  + (size_t)e * H_ * D_;

  const int tid  = threadIdx.x;
  const int w    = tid >> 6;
  const int lane = tid & 63;
  const int wr = w >> 1, wc = w & 1;
  const int lr = lane & 15;
  const int lk = lane >> 4;

  const int g0 = 2 * w, g1 = 2 * w + 1;
  const unsigned short* ga0 = Ae + (size_t)(m0 + g0 * 16 + lr) * H_ + lk * 8;
  const unsigned short* ga1 = Ae + (size_t)(m0 + g1 * 16 + lr) * H_ + lk * 8;
  const unsigned short* gb0 = Be + (size_t)(n0 + g0 * 16 + lr) * H_ + lk * 8;
  const unsigned short* gb1 = Be + (size_t)(n0 + g1 * 16 + lr) * H_ + lk * 8;
  unsigned short* la0 = sA + g0 * 512;
  unsigned short* la1 = sA + g1 * 512;
  unsigned short* lb0 = sB + g0 * 512;
  unsigned short* lb1 = sB + g1 * 512;

  const unsigned short* rA = sA + (wr * 4) * 512 + lane * 8;
  const unsigned short* rB = sB + (wc * 4) * 512 + lane * 8;

  f32x4 acc[4][4] = {};

  for (int kt = 0; kt < H_ / 32; ++kt) {
    const int ko = kt * 32;
    gld16(ga0 + ko, la0);
    gld16(ga1 + ko, la1);
    gld16(gb0 + ko, lb0);
    gld16(gb1 + ko, lb1);
    __syncthreads();
    bf16x8 af[4], bf[4];
#pragma unroll
    for (int i = 0; i < 4; ++i) af[i] = *(const bf16x8*)(rA + i * 512);
#pragma unroll
    for (int j = 0; j < 4; ++j) bf[j] = *(const bf16x8*)(rB + j * 512);
#pragma unroll
    for (int i = 0; i < 4; ++i)
#pragma unroll
      for (int j = 0; j < 4; ++j)
        acc[i][j] = mfma_bf16(af[i], bf[j], acc[i][j]);
    __syncthreads();
  }

  float* Oe = out + (size_t)e * TPE * D_;
  const int rbase = m0 + wr * 64;
  const int cbase = n0 + wc * 64;
#pragma unroll
  for (int i = 0; i < 4; ++i)
#pragma unroll
    for (int j = 0; j < 4; ++j)
#pragma unroll
      for (int r = 0; r < 4; ++r) {
        int row = rbase + i * 16 + lk * 4 + r;
        int col = cbase + j * 16 + lr;
        Oe[(size_t)row * D_ + col] = acc[i][j][r];
      }
}

extern "C" void kernel_launch(void* const* d_in, const int* in_sizes, int n_in,
                              void* d_out, int out_size, void* d_ws, size_t ws_size,
                              hipStream_t stream) {
  const float* x  = (const float*)d_in[0];
  const float* w1 = (const float*)d_in[1];
  const float* w2 = (const float*)d_in[2];
  const float* w3 = (const float*)d_in[3];
  // d_in[4] = splits (uniform T/E, unused)

  char* ws = (char*)d_ws;
  unsigned short* xb   = (unsigned short*)(ws);                         // 64 MB
  unsigned short* w1t  = (unsigned short*)(ws + 67108864ull);           // 64 MB
  unsigned short* w3t  = (unsigned short*)(ws + 134217728ull);          // 64 MB
  unsigned short* w2t  = (unsigned short*)(ws + 201326592ull);          // 64 MB
  unsigned short* hbuf = (unsigned short*)(ws + 268435456ull);          // 256 MB
  float* out = (float*)d_out;

  // 1) convert / transpose to bf16
  cvt_bf16<<<(T_ * D_) / 2048, 256, 0, stream>>>(x, xb);
  transpose_bf16<<<dim3(H_ / 64, D_ / 64, E_), 256, 0, stream>>>(w1, w1t, D_, H_);
  transpose_bf16<<<dim3(H_ / 64, D_ / 64, E_), 256, 0, stream>>>(w3, w3t, D_, H_);
  transpose_bf16<<<dim3(D_ / 64, H_ / 64, E_), 256, 0, stream>>>(w2, w2t, H_, D_);

  // 2) gate/up + SwiGLU -> h
  gemm_gateup<<<dim3(TPE / 128, H_ / 128, E_), 256, 0, stream>>>(xb, w1t, w3t, hbuf);

  // 3) down projection -> out
  gemm_down<<<dim3(TPE / 128, D_ / 128, E_), 256, 0, stream>>>(hbuf, w2t, out);
}